// Round 2
// baseline (3027.149 us; speedup 1.0000x reference)
//
#include <hip/hip_runtime.h>

// VectorQuantizer: z [8192,1024] f32, embed [4096,256] f32
// outputs (flat f32): quantized_st [8388608], indices [32768], loss, codebook_loss, commitment_loss, perplexity

constexpr int D_CODE  = 256;
constexpr int M_ROWS  = 32768;       // 8192*4
constexpr int K_EMB   = 4096;
constexpr long Q_ELEMS = 8388608L;   // 8192*1024

typedef float v2f __attribute__((ext_vector_type(2)));

// workspace layout (bytes)
constexpr size_t OFF_SUMZ = 0;         // 32768 f32  (128 KB)
constexpr size_t OFF_SUME = 131072;    // 4096 f32   (16 KB)
constexpr size_t OFF_BEST = 147456;    // 32768 u64  (256 KB)
constexpr size_t OFF_IDX  = 409600;    // 32768 i32  (128 KB)
constexpr size_t OFF_HIST = 540672;    // 4096 u32   (16 KB)
constexpr size_t OFF_DACC = 557056;    // 1 double
constexpr size_t ZERO_LEN = 16392;     // hist + dacc (contiguous)

__device__ __forceinline__ unsigned long long umin64(unsigned long long a, unsigned long long b) {
  return a < b ? a : b;
}

// ---------------- kernel 1: row sums of squares (z and embed) ----------------
__global__ __launch_bounds__(256) void k_rowsums(const float* __restrict__ z,
                                                 const float* __restrict__ emb,
                                                 float* __restrict__ sumz,
                                                 float* __restrict__ sume) {
  int w = threadIdx.x >> 6, lane = threadIdx.x & 63;
  int row = blockIdx.x * 4 + w;                  // 0..36863
  const float* src;
  float* dst;
  if (row < M_ROWS) { src = z + (size_t)row * D_CODE; dst = sumz + row; }
  else              { src = emb + (size_t)(row - M_ROWS) * D_CODE; dst = sume + (row - M_ROWS); }
  float4 v = *(const float4*)(src + lane * 4);
  // any summation order is fine: argmin is invariant to grid shifts (binade-commuting rounding)
  float s = (v.x * v.x + v.y * v.y) + (v.z * v.z + v.w * v.w);
  #pragma unroll
  for (int off = 32; off; off >>= 1) s += __shfl_xor(s, off, 64);
  if (lane == 0) *dst = s;
}

// ---------------- kernel 2: fused fp32 distance + argmin ----------------
// grid = 128 row-tiles x 8 cand-slices = 1024 blocks (4 blocks/CU).
// block: 256 thr; tx = tid&7 (8 cand lanes), ty = tid>>3 (32 row groups x 8 rows = 256 rows).
// per thread: 8 rows x 4 cands, acc paired across K (even/odd partial sums) -> v_pk_fma_f32.
// e-tile [32 cands][256 k] in LDS, pitch 260 floats: tx-lane read stride 1040B -> banks 4tx..4tx+3
// (all 32 banks once, ty broadcast) -> conflict-free ds_read_b128.
__global__ __launch_bounds__(256, 4) void k_argmin(const float* __restrict__ z,
                                                   const float* __restrict__ emb,
                                                   const float* __restrict__ sumz,
                                                   const float* __restrict__ sume,
                                                   unsigned long long* __restrict__ best64) {
  __shared__ float ebuf[32][260];                 // 33.3 KB

  const int tid = threadIdx.x;
  const int tx = tid & 7;
  const int ty = tid >> 3;
  const int rt = blockIdx.x >> 3;                 // 0..127
  const int q  = blockIdx.x & 7;                  // 0..7
  const int row0 = rt * 256;
  const int c00 = q * 512;

  const float* zb = z + ((size_t)row0 + (size_t)ty * 8) * D_CODE;

  float sz[8];
  #pragma unroll
  for (int i = 0; i < 8; ++i) sz[i] = sumz[row0 + ty * 8 + i];

  const int scc = tid & 31;                       // staging: candidate within tile
  const int sch = tid >> 5;                       // staging: 32-float chunk along k

  #pragma unroll 1
  for (int et = 0; et < 16; ++et) {
    const int c0 = c00 + et * 32;

    // ---- stage e-tile [32][256] ----
    __syncthreads();                              // previous tile's readers done
    {
      const float* src = emb + (size_t)(c0 + scc) * D_CODE + sch * 32;
      float* dst = &ebuf[scc][sch * 32];
      #pragma unroll
      for (int w = 0; w < 8; ++w)
        *(float4*)(dst + w * 4) = *(const float4*)(src + w * 4);
    }
    __syncthreads();                              // tile visible

    // ---- accumulate: acc[i][j] = (sum over even k, sum over odd k) ----
    v2f acc[8][4];
    #pragma unroll
    for (int i = 0; i < 8; ++i)
      #pragma unroll
      for (int j = 0; j < 4; ++j) acc[i][j] = (v2f)(0.0f);

    #pragma unroll 1
    for (int kc = 0; kc < 64; ++kc) {             // 4 k per step
      v2f e0[4], e1[4];
      #pragma unroll
      for (int j = 0; j < 4; ++j) {
        float4 ev = *(const float4*)&ebuf[j * 8 + tx][kc * 4];
        e0[j] = (v2f){ev.x, ev.y};
        e1[j] = (v2f){ev.z, ev.w};
      }
      #pragma unroll
      for (int i = 0; i < 8; ++i) {
        float4 zv = *(const float4*)(zb + (size_t)i * D_CODE + kc * 4);
        v2f za = (v2f){zv.x, zv.y};
        v2f zc = (v2f){zv.z, zv.w};
        #pragma unroll
        for (int j = 0; j < 4; ++j) {
          acc[i][j] = __builtin_elementwise_fma(za, e0[j], acc[i][j]);
          acc[i][j] = __builtin_elementwise_fma(zc, e1[j], acc[i][j]);
        }
      }
    }

    // ---- epilogue: literal fp32 distance, first-index tie-break, u64 min ----
    unsigned long long bestRow[8];
    #pragma unroll
    for (int i = 0; i < 8; ++i) bestRow[i] = ~0ULL;
    #pragma unroll
    for (int j = 0; j < 4; ++j) {
      int cg = c0 + j * 8 + tx;
      float se = sume[cg];
      #pragma unroll
      for (int i = 0; i < 8; ++i) {
        float dot = acc[i][j].x + acc[i][j].y;    // even + odd partials (~1e-9 vs ref order, << ulp grid)
        float dd = (sz[i] - 2.0f * dot) + se;     // same roundings as the reference expression
        unsigned long long key =
            ((unsigned long long)__float_as_uint(dd) << 32) | (unsigned int)cg;
        bestRow[i] = umin64(bestRow[i], key);
      }
    }
    #pragma unroll
    for (int i = 0; i < 8; ++i) {
      unsigned long long b = bestRow[i];
      b = umin64(b, __shfl_xor(b, 1, 8));
      b = umin64(b, __shfl_xor(b, 2, 8));
      b = umin64(b, __shfl_xor(b, 4, 8));
      if (tx == 0) atomicMin(&best64[row0 + ty * 8 + i], b);
    }
  }
}

// ---------------- kernel 3: emit indices + histogram ----------------
__global__ __launch_bounds__(256) void k_merge(const unsigned long long* __restrict__ best64,
                                               int* __restrict__ idx,
                                               float* __restrict__ outI,
                                               unsigned int* __restrict__ hist) {
  int r = blockIdx.x * 256 + threadIdx.x;
  unsigned long long b = best64[r];
  int id = (int)(unsigned int)(b & 0xffffffffULL);
  idx[r] = id;
  outI[r] = (float)id;
  atomicAdd(&hist[id], 1u);
}

// ---------------- kernel 4: quantized_st (bit-exact) + commitment accumulator ----------------
__global__ __launch_bounds__(256) void k_quant(const float* __restrict__ z,
                                               const float* __restrict__ emb,
                                               const int* __restrict__ idx,
                                               float* __restrict__ outQ,
                                               double* __restrict__ dacc) {
  __shared__ double sd[256];
  const long NF4 = Q_ELEMS / 4;                    // 2097152 float4
  long f0 = (long)blockIdx.x * 256 + threadIdx.x;  // 524288 threads
  double s = 0.0;
  for (long f = f0; f < NF4; f += 524288) {
    long m = f >> 6;                               // flat_z row
    int d4 = (int)(f & 63) * 4;
    int id = idx[m];
    float4 zv = *(const float4*)(z + f * 4);
    float4 qv = *(const float4*)(emb + (size_t)id * D_CODE + d4);
    float dx = qv.x - zv.x, dy = qv.y - zv.y, dz = qv.z - zv.z, dw = qv.w - zv.w;
    float4 ov;
    ov.x = zv.x + dx; ov.y = zv.y + dy; ov.z = zv.z + dz; ov.w = zv.w + dw;  // z + (q - z), literal
    *(float4*)(outQ + f * 4) = ov;
    s += (double)dx * (double)dx + (double)dy * (double)dy
       + (double)dz * (double)dz + (double)dw * (double)dw;
  }
  sd[threadIdx.x] = s;
  __syncthreads();
  #pragma unroll
  for (int o = 128; o; o >>= 1) {
    if (threadIdx.x < o) sd[threadIdx.x] += sd[threadIdx.x + o];
    __syncthreads();
  }
  if (threadIdx.x == 0) atomicAdd(dacc, sd[0]);
}

// ---------------- kernel 5: scalars ----------------
__global__ __launch_bounds__(256) void k_final(const unsigned int* __restrict__ hist,
                                               const double* __restrict__ dacc,
                                               float* __restrict__ outS) {
  __shared__ double sd[256];
  double s = 0.0;
  for (int c = threadIdx.x; c < K_EMB; c += 256) {
    double p = (double)hist[c] * (1.0 / 32768.0);
    s += p * log(p + 1e-10);
  }
  sd[threadIdx.x] = s;
  __syncthreads();
  #pragma unroll
  for (int o = 128; o; o >>= 1) {
    if (threadIdx.x < o) sd[threadIdx.x] += sd[threadIdx.x + o];
    __syncthreads();
  }
  if (threadIdx.x == 0) {
    float commit = (float)(dacc[0] / (double)Q_ELEMS);
    outS[0] = 0.25f * commit;   // loss = 1.0*0 + 0.25*commitment
    outS[1] = 0.0f;             // codebook_loss (EMA eval mode)
    outS[2] = commit;           // commitment_loss
    outS[3] = (float)exp(-sd[0]);  // perplexity
  }
}

extern "C" void kernel_launch(void* const* d_in, const int* in_sizes, int n_in,
                              void* d_out, int out_size, void* d_ws, size_t ws_size,
                              hipStream_t stream) {
  const float* z   = (const float*)d_in[0];
  const float* emb = (const float*)d_in[1];
  float* out = (float*)d_out;
  char* ws = (char*)d_ws;

  float* sumz = (float*)(ws + OFF_SUMZ);
  float* sume = (float*)(ws + OFF_SUME);
  unsigned long long* best64 = (unsigned long long*)(ws + OFF_BEST);
  int* idx = (int*)(ws + OFF_IDX);
  unsigned int* hist = (unsigned int*)(ws + OFF_HIST);
  double* dacc = (double*)(ws + OFF_DACC);

  hipMemsetAsync(ws + OFF_HIST, 0, ZERO_LEN, stream);    // hist + dacc
  hipMemsetAsync(ws + OFF_BEST, 0xFF, 262144, stream);   // best64 = ~0

  k_rowsums<<<9216, 256, 0, stream>>>(z, emb, sumz, sume);
  k_argmin<<<1024, 256, 0, stream>>>(z, emb, sumz, sume, best64);
  k_merge<<<M_ROWS / 256, 256, 0, stream>>>(best64, idx, out + Q_ELEMS, hist);
  k_quant<<<2048, 256, 0, stream>>>(z, emb, idx, out, dacc);
  k_final<<<1, 256, 0, stream>>>(hist, dacc, out + Q_ELEMS + M_ROWS);
}

// Round 3
// 1347.331 us; speedup vs baseline: 2.2468x; 2.2468x over previous
//
#include <hip/hip_runtime.h>

// VectorQuantizer: z [8192,1024] f32, embed [4096,256] f32
// outputs (flat f32): quantized_st [8388608], indices [32768], loss, codebook_loss, commitment_loss, perplexity

constexpr int D_CODE  = 256;
constexpr int M_ROWS  = 32768;       // 8192*4
constexpr int K_EMB   = 4096;
constexpr long Q_ELEMS = 8388608L;   // 8192*1024

// workspace layout (bytes)
constexpr size_t OFF_SUMZ = 0;         // 32768 f32  (128 KB)
constexpr size_t OFF_SUME = 131072;    // 4096 f32   (16 KB)
constexpr size_t OFF_BEST = 147456;    // 32768 u64  (256 KB)
constexpr size_t OFF_IDX  = 409600;    // 32768 i32  (128 KB)
constexpr size_t OFF_HIST = 540672;    // 4096 u32   (16 KB)
constexpr size_t OFF_DACC = 557056;    // 1 double
constexpr size_t ZERO_LEN = 16392;     // hist + dacc (contiguous)

__device__ __forceinline__ unsigned long long umin64(unsigned long long a, unsigned long long b) {
  return a < b ? a : b;
}

// ---------------- kernel 1: row sums of squares (z and embed) ----------------
__global__ __launch_bounds__(256) void k_rowsums(const float* __restrict__ z,
                                                 const float* __restrict__ emb,
                                                 float* __restrict__ sumz,
                                                 float* __restrict__ sume) {
  int w = threadIdx.x >> 6, lane = threadIdx.x & 63;
  int row = blockIdx.x * 4 + w;                  // 0..36863
  const float* src;
  float* dst;
  if (row < M_ROWS) { src = z + (size_t)row * D_CODE; dst = sumz + row; }
  else              { src = emb + (size_t)(row - M_ROWS) * D_CODE; dst = sume + (row - M_ROWS); }
  float4 v = *(const float4*)(src + lane * 4);
  // any summation order is fine: argmin is invariant to grid shifts (binade-commuting rounding)
  float s = (v.x * v.x + v.y * v.y) + (v.z * v.z + v.w * v.w);
  #pragma unroll
  for (int off = 32; off; off >>= 1) s += __shfl_xor(s, off, 64);
  if (lane == 0) *dst = s;
}

// ---------------- kernel 2: fused fp32 distance + argmin ----------------
// grid = 32 q-slices x 128 row-tiles, bid = q*128 + rt  ->  XCD = rt%8: the 32 q-siblings of a
// row-tile land on ONE XCD and share its z rows in that XCD's L2 (z HBM ~ compulsory only).
// block: 256 thr; tx = tid&7 (8 cand lanes x 16 cands), ty = tid>>3 (32 groups x 8 rows).
// Per 32-k phase both operands are staged to LDS; the compute loop touches NO global memory:
//   zbuf [32 k][264]  transposed, row index XOR-swizzled by ((k>>2)&7)<<3  -> 2-way banks (free)
//   ebuf [32 k][132]  (R1's proven layout)                                 -> conflict-free
__global__ __launch_bounds__(256, 3) void k_argmin(const float* __restrict__ z,
                                                   const float* __restrict__ emb,
                                                   const float* __restrict__ sumz,
                                                   const float* __restrict__ sume,
                                                   unsigned long long* __restrict__ best64) {
  __shared__ float zbuf[32][264];                 // 33.0 KB
  __shared__ float ebuf[32][132];                 // 16.5 KB   (total 50.7 KB -> 3 blocks/CU)

  const int tid = threadIdx.x;
  const int tx = tid & 7;
  const int ty = tid >> 3;
  const int rt = blockIdx.x & 127;
  const int q  = blockIdx.x >> 7;                 // 0..31
  const int row0 = rt * 256;
  const int c0 = q * 128;

  float acc[8][16];
  #pragma unroll
  for (int i = 0; i < 8; ++i)
    #pragma unroll
    for (int j = 0; j < 16; ++j) acc[i][j] = 0.0f;

  const int zr8 = tid >> 3;                       // z-stage: row within 32-row group
  const int zkq = tid & 7;                        // z-stage: k-quad 0..7

  #pragma unroll 1
  for (int kk = 0; kk < 8; ++kk) {                // 32-k phases
    __syncthreads();                              // previous phase's readers done

    // ---- stage z[256 rows][32 k] -> zbuf[k][row^swz], coalesced 128B-per-row reads ----
    #pragma unroll 2
    for (int p = 0; p < 8; ++p) {
      int row = p * 32 + zr8;
      float4 v = *(const float4*)(z + (size_t)(row0 + row) * D_CODE + kk * 32 + zkq * 4);
      int rsw = row ^ (zkq << 3);                 // swizzle: k-quad = zkq
      zbuf[4 * zkq + 0][rsw] = v.x;
      zbuf[4 * zkq + 1][rsw] = v.y;
      zbuf[4 * zkq + 2][rsw] = v.z;
      zbuf[4 * zkq + 3][rsw] = v.w;
    }

    // ---- stage e[128 cands][32 k] -> ebuf[k][c] ----
    #pragma unroll
    for (int p = 0; p < 4; ++p) {
      int g = 4 * tid + p;
      int cc = g >> 3, kq2 = g & 7;
      float4 s = *(const float4*)(emb + (size_t)(c0 + cc) * D_CODE + kk * 32 + kq2 * 4);
      ebuf[4 * kq2 + 0][cc] = s.x;
      ebuf[4 * kq2 + 1][cc] = s.y;
      ebuf[4 * kq2 + 2][cc] = s.z;
      ebuf[4 * kq2 + 3][cc] = s.w;
    }
    __syncthreads();                              // tiles visible

    // ---- compute: 8 kq x 4 kr x (8 rows x 16 cands) FMA, all operands from LDS ----
    #pragma unroll 1
    for (int kq = 0; kq < 8; ++kq) {
      const float* zrow = &zbuf[4 * kq][(ty ^ kq) << 3];
      const float* erow = &ebuf[4 * kq][tx << 2];
      #pragma unroll
      for (int kr = 0; kr < 4; ++kr) {
        float4 za = *(const float4*)(zrow + kr * 264);
        float4 zb4 = *(const float4*)(zrow + kr * 264 + 4);
        float zr[8] = {za.x, za.y, za.z, za.w, zb4.x, zb4.y, zb4.z, zb4.w};
        #pragma unroll
        for (int g4 = 0; g4 < 4; ++g4) {
          float4 ef = *(const float4*)(erow + kr * 132 + g4 * 32);
          #pragma unroll
          for (int i = 0; i < 8; ++i) {
            acc[i][4 * g4 + 0] = fmaf(zr[i], ef.x, acc[i][4 * g4 + 0]);
            acc[i][4 * g4 + 1] = fmaf(zr[i], ef.y, acc[i][4 * g4 + 1]);
            acc[i][4 * g4 + 2] = fmaf(zr[i], ef.z, acc[i][4 * g4 + 2]);
            acc[i][4 * g4 + 3] = fmaf(zr[i], ef.w, acc[i][4 * g4 + 3]);
          }
        }
      }
    }
  }

  // ---- epilogue: literal fp32 distance d = (sumz - 2*dot) + sume, first-index tie-break ----
  unsigned long long bestRow[8];
  #pragma unroll
  for (int i = 0; i < 8; ++i) bestRow[i] = ~0ULL;
  float sz[8];
  #pragma unroll
  for (int i = 0; i < 8; ++i) sz[i] = sumz[row0 + ty * 8 + i];
  #pragma unroll
  for (int g4 = 0; g4 < 4; ++g4) {
    #pragma unroll
    for (int l = 0; l < 4; ++l) {
      int j = 4 * g4 + l;
      int cg = c0 + g4 * 32 + tx * 4 + l;
      float se = sume[cg];
      #pragma unroll
      for (int i = 0; i < 8; ++i) {
        float dd = (sz[i] - 2.0f * acc[i][j]) + se;   // same roundings as the reference
        unsigned long long key =
            ((unsigned long long)__float_as_uint(dd) << 32) | (unsigned int)cg;
        bestRow[i] = umin64(bestRow[i], key);
      }
    }
  }
  #pragma unroll
  for (int i = 0; i < 8; ++i) {
    unsigned long long b = bestRow[i];
    b = umin64(b, __shfl_xor(b, 1, 8));
    b = umin64(b, __shfl_xor(b, 2, 8));
    b = umin64(b, __shfl_xor(b, 4, 8));
    if (tx == 0) atomicMin(&best64[row0 + ty * 8 + i], b);
  }
}

// ---------------- kernel 3: emit indices + histogram ----------------
__global__ __launch_bounds__(256) void k_merge(const unsigned long long* __restrict__ best64,
                                               int* __restrict__ idx,
                                               float* __restrict__ outI,
                                               unsigned int* __restrict__ hist) {
  int r = blockIdx.x * 256 + threadIdx.x;
  unsigned long long b = best64[r];
  int id = (int)(unsigned int)(b & 0xffffffffULL);
  idx[r] = id;
  outI[r] = (float)id;
  atomicAdd(&hist[id], 1u);
}

// ---------------- kernel 4: quantized_st (bit-exact) + commitment accumulator ----------------
__global__ __launch_bounds__(256) void k_quant(const float* __restrict__ z,
                                               const float* __restrict__ emb,
                                               const int* __restrict__ idx,
                                               float* __restrict__ outQ,
                                               double* __restrict__ dacc) {
  __shared__ double sd[256];
  const long NF4 = Q_ELEMS / 4;                    // 2097152 float4
  long f0 = (long)blockIdx.x * 256 + threadIdx.x;  // 524288 threads
  double s = 0.0;
  for (long f = f0; f < NF4; f += 524288) {
    long m = f >> 6;                               // flat_z row
    int d4 = (int)(f & 63) * 4;
    int id = idx[m];
    float4 zv = *(const float4*)(z + f * 4);
    float4 qv = *(const float4*)(emb + (size_t)id * D_CODE + d4);
    float dx = qv.x - zv.x, dy = qv.y - zv.y, dz = qv.z - zv.z, dw = qv.w - zv.w;
    float4 ov;
    ov.x = zv.x + dx; ov.y = zv.y + dy; ov.z = zv.z + dz; ov.w = zv.w + dw;  // z + (q - z), literal
    *(float4*)(outQ + f * 4) = ov;
    s += (double)dx * (double)dx + (double)dy * (double)dy
       + (double)dz * (double)dz + (double)dw * (double)dw;
  }
  sd[threadIdx.x] = s;
  __syncthreads();
  #pragma unroll
  for (int o = 128; o; o >>= 1) {
    if (threadIdx.x < o) sd[threadIdx.x] += sd[threadIdx.x + o];
    __syncthreads();
  }
  if (threadIdx.x == 0) atomicAdd(dacc, sd[0]);
}

// ---------------- kernel 5: scalars ----------------
__global__ __launch_bounds__(256) void k_final(const unsigned int* __restrict__ hist,
                                               const double* __restrict__ dacc,
                                               float* __restrict__ outS) {
  __shared__ double sd[256];
  double s = 0.0;
  for (int c = threadIdx.x; c < K_EMB; c += 256) {
    double p = (double)hist[c] * (1.0 / 32768.0);
    s += p * log(p + 1e-10);
  }
  sd[threadIdx.x] = s;
  __syncthreads();
  #pragma unroll
  for (int o = 128; o; o >>= 1) {
    if (threadIdx.x < o) sd[threadIdx.x] += sd[threadIdx.x + o];
    __syncthreads();
  }
  if (threadIdx.x == 0) {
    float commit = (float)(dacc[0] / (double)Q_ELEMS);
    outS[0] = 0.25f * commit;   // loss = 1.0*0 + 0.25*commitment
    outS[1] = 0.0f;             // codebook_loss (EMA eval mode)
    outS[2] = commit;           // commitment_loss
    outS[3] = (float)exp(-sd[0]);  // perplexity
  }
}

extern "C" void kernel_launch(void* const* d_in, const int* in_sizes, int n_in,
                              void* d_out, int out_size, void* d_ws, size_t ws_size,
                              hipStream_t stream) {
  const float* z   = (const float*)d_in[0];
  const float* emb = (const float*)d_in[1];
  float* out = (float*)d_out;
  char* ws = (char*)d_ws;

  float* sumz = (float*)(ws + OFF_SUMZ);
  float* sume = (float*)(ws + OFF_SUME);
  unsigned long long* best64 = (unsigned long long*)(ws + OFF_BEST);
  int* idx = (int*)(ws + OFF_IDX);
  unsigned int* hist = (unsigned int*)(ws + OFF_HIST);
  double* dacc = (double*)(ws + OFF_DACC);

  hipMemsetAsync(ws + OFF_HIST, 0, ZERO_LEN, stream);    // hist + dacc
  hipMemsetAsync(ws + OFF_BEST, 0xFF, 262144, stream);   // best64 = ~0

  k_rowsums<<<9216, 256, 0, stream>>>(z, emb, sumz, sume);
  k_argmin<<<4096, 256, 0, stream>>>(z, emb, sumz, sume, best64);
  k_merge<<<M_ROWS / 256, 256, 0, stream>>>(best64, idx, out + Q_ELEMS, hist);
  k_quant<<<2048, 256, 0, stream>>>(z, emb, idx, out, dacc);
  k_final<<<1, 256, 0, stream>>>(hist, dacc, out + Q_ELEMS + M_ROWS);
}